// Round 1
// baseline (338.696 us; speedup 1.0000x reference)
//
#include <hip/hip_runtime.h>

#define NP 2000   // points
#define PP 2048   // padded points
#define NB 128    // N*t
#define NC 64     // channels

// ---- ws byte layout ----
// [0,256):       touched-pixel masks, 64 u32 (l1: words 0..31, l2: 32..39, l3: 40..41)
// [4096, ...):   params int x0[4][PP], int y0[4][PP], float wx[4][PP], float wy[4][PP]
// [256K, ...):   pooled level1 [128][64][32][32] f32  (33.55 MB)
//                pooled level2 [128][64][16][16] f32  ( 8.39 MB)
//                pooled level3 [128][64][ 8][ 8] f32  ( 2.10 MB)
#define MASK_OFF 0u
#define X0_OFF   4096u
#define Y0_OFF   (X0_OFF + 4u*PP*4u)
#define WX_OFF   (Y0_OFF + 4u*PP*4u)
#define WY_OFF   (WX_OFF + 4u*PP*4u)
#define P1_OFF   262144u
#define P2_OFF   (P1_OFF + 33554432u)
#define P3_OFF   (P2_OFF + 8388608u)

// K1: per-point, per-level sampling params + touched-pixel bitmaps. One block.
__global__ __launch_bounds__(256) void k1_params(const float* __restrict__ grid,
                          unsigned* __restrict__ masks,
                          int* __restrict__ x0a, int* __restrict__ y0a,
                          float* __restrict__ wxa, float* __restrict__ wya) {
  __shared__ unsigned smask[64];
  int tid = threadIdx.x;
  if (tid < 64) smask[tid] = 0u;
  __syncthreads();
  for (int p = tid; p < PP; p += 256) {
    bool valid = (p < NP);
    float gx = 0.f, gy = 0.f;
    if (valid) {
      gx = fminf(1.f, fmaxf(-1.f, grid[2*p]));
      gy = fminf(1.f, fmaxf(-1.f, grid[2*p+1]));
    }
    for (int l = 0; l < 4; l++) {
      int W = 64 >> l;
      float ix = (gx + 1.f) * 0.5f * (float)(W - 1);
      float iy = (gy + 1.f) * 0.5f * (float)(W - 1);
      int x0 = (int)floorf(ix); if (x0 > W - 2) x0 = W - 2;
      int y0 = (int)floorf(iy); if (y0 > W - 2) y0 = W - 2;
      // when the ref would clamp x1 (ix==W-1), here wx==1 and weight shifts to x0+1:
      // algebraically identical to the ref's (x0=W-1, wx=0, x1 clamped) case.
      float wx = ix - (float)x0;
      float wy = iy - (float)y0;
      if (!valid) { x0 = 0; y0 = 0; wx = 0.f; wy = 0.f; }
      x0a[l*PP+p] = x0; y0a[l*PP+p] = y0; wxa[l*PP+p] = wx; wya[l*PP+p] = wy;
      if (valid && l >= 1) {
        int wb = (l==1) ? 0 : ((l==2) ? 32 : 40);
        int i00 = y0*W + x0;
        atomicOr(&smask[wb + (i00>>5)], 1u << (i00 & 31));
        atomicOr(&smask[wb + ((i00+1)>>5)], 1u << ((i00+1) & 31));
        int i10 = i00 + W;
        atomicOr(&smask[wb + (i10>>5)], 1u << (i10 & 31));
        atomicOr(&smask[wb + ((i10+1)>>5)], 1u << ((i10+1) & 31));
      }
    }
  }
  __syncthreads();
  if (tid < 64) masks[tid] = smask[tid];
}

// K2: pooled values for touched pixels only. grid=(1344, 32), block=256 (thread = plane).
template<int L>
__device__ __forceinline__ void pool_px(const float* __restrict__ x, float* __restrict__ dst,
                                        int idx, int plane) {
  constexpr int W = 64 >> L;
  constexpr int S = 1 << L;
  int y = idx / W, xq = idx - y*W;
  int b = plane >> 6, ch = plane & 63;
  int n = b >> 4, tt = b & 15;
  const float* src = x + ((size_t)((((n<<6)|ch)<<4) | tt) << 12) + (y*S)*64 + xq*S;
  float s = 0.f;
  #pragma unroll
  for (int r = 0; r < S; r++) {
    #pragma unroll
    for (int c = 0; c < S; c++) s += src[r*64 + c];
  }
  dst[(size_t)plane*(W*W) + idx] = s * (1.f/(float)(S*S));
}

__global__ __launch_bounds__(256) void k2_pool(const float* __restrict__ x,
                        const unsigned* __restrict__ masks,
                        float* __restrict__ p1, float* __restrict__ p2, float* __restrict__ p3) {
  int bx = blockIdx.x;
  int plane = blockIdx.y*256 + threadIdx.x;   // b*64+ch, 0..8191
  if (bx < 1024) {
    if (!((masks[bx>>5] >> (bx&31)) & 1u)) return;
    pool_px<1>(x, p1, bx, plane);
  } else if (bx < 1280) {
    int idx = bx - 1024;
    if (!((masks[32 + (idx>>5)] >> (idx&31)) & 1u)) return;
    pool_px<2>(x, p2, idx, plane);
  } else {
    int idx = bx - 1280;
    if (!((masks[40 + (idx>>5)] >> (idx&31)) & 1u)) return;
    pool_px<3>(x, p3, idx, plane);
  }
}

// K3: lane = point; loop (level, channel); per-corner accumulators; weight-combine per level.
template<int W>
__device__ __forceinline__ float level_sum(const float* __restrict__ Lp, int planeStride,
                                           const float* __restrict__ fp,
                                           float wx, float wy) {
  float w11 = wx*wy;
  float w01 = wx - w11;
  float w10 = wy - w11;
  float w00 = 1.f - wx - wy + w11;
  float A00 = 0.f, A01 = 0.f, A10 = 0.f, A11 = 0.f;
  #pragma unroll 8
  for (int k = 0; k < 64; k++) {
    float a = Lp[0], b = Lp[1], c = Lp[W], d = Lp[W+1];
    float f = fp[0];
    A00 += f*a; A01 += f*b; A10 += f*c; A11 += f*d;
    Lp += planeStride; fp += NP;
  }
  return w00*A00 + w01*A01 + w10*A10 + w11*A11;
}

__global__ __launch_bounds__(256) void k3_main(const float* __restrict__ x,
    const float* __restrict__ feat, const float* __restrict__ bias,
    const float* __restrict__ p1, const float* __restrict__ p2, const float* __restrict__ p3,
    const int* __restrict__ x0a, const int* __restrict__ y0a,
    const float* __restrict__ wxa, const float* __restrict__ wya,
    float* __restrict__ out) {
  int p = blockIdx.x*256 + threadIdx.x;     // 0..2047
  int pc = (p < NP) ? p : (NP - 1);         // clamp so pad threads stay in-bounds
  int b = blockIdx.y;
  int n = b >> 4, tt = b & 15;
  float acc = 0.f;
  {
    int x0 = x0a[pc], y0 = y0a[pc];
    const float* Lp = x + ((size_t)(((n<<6)<<4) | tt) << 12) + y0*64 + x0;
    acc += level_sum<64>(Lp, 65536, feat + pc, wxa[pc], wya[pc]);
  }
  {
    int x0 = x0a[PP+pc], y0 = y0a[PP+pc];
    const float* Lp = p1 + (size_t)(b*64)*1024 + y0*32 + x0;
    acc += level_sum<32>(Lp, 1024, feat + 64*NP + pc, wxa[PP+pc], wya[PP+pc]);
  }
  {
    int x0 = x0a[2*PP+pc], y0 = y0a[2*PP+pc];
    const float* Lp = p2 + (size_t)(b*64)*256 + y0*16 + x0;
    acc += level_sum<16>(Lp, 256, feat + 128*NP + pc, wxa[2*PP+pc], wya[2*PP+pc]);
  }
  {
    int x0 = x0a[3*PP+pc], y0 = y0a[3*PP+pc];
    const float* Lp = p3 + (size_t)(b*64)*64 + y0*8 + x0;
    acc += level_sum<8>(Lp, 64, feat + 192*NP + pc, wxa[3*PP+pc], wya[3*PP+pc]);
  }
  if (p < NP) out[b*NP + p] = acc + bias[p];
}

extern "C" void kernel_launch(void* const* d_in, const int* in_sizes, int n_in,
                              void* d_out, int out_size, void* d_ws, size_t ws_size,
                              hipStream_t stream) {
  (void)in_sizes; (void)n_in; (void)out_size; (void)ws_size;
  const float* x    = (const float*)d_in[0];
  const float* grid = (const float*)d_in[1];
  const float* feat = (const float*)d_in[2];
  const float* bias = (const float*)d_in[3];
  float* out = (float*)d_out;
  char* ws = (char*)d_ws;
  unsigned* masks = (unsigned*)(ws + MASK_OFF);
  int*   x0a = (int*)(ws + X0_OFF);
  int*   y0a = (int*)(ws + Y0_OFF);
  float* wxa = (float*)(ws + WX_OFF);
  float* wya = (float*)(ws + WY_OFF);
  float* p1  = (float*)(ws + P1_OFF);
  float* p2  = (float*)(ws + P2_OFF);
  float* p3  = (float*)(ws + P3_OFF);

  k1_params<<<1, 256, 0, stream>>>(grid, masks, x0a, y0a, wxa, wya);
  k2_pool<<<dim3(1344, 32), 256, 0, stream>>>(x, masks, p1, p2, p3);
  k3_main<<<dim3(8, 128), 256, 0, stream>>>(x, feat, bias, p1, p2, p3,
                                            x0a, y0a, wxa, wya, out);
}

// Round 2
// 297.880 us; speedup vs baseline: 1.1370x; 1.1370x over previous
//
#include <hip/hip_runtime.h>

#define NP 2000   // points
#define PP 2048   // padded points
#define NB 128    // N*t planes-batches
#define NC 64     // channels

// window caps per level (square)
#define C0 16
#define C1 8
#define C2 4
#define C3 4
// pixel offsets of each level's window inside a plane slab
#define OFF0 0
#define OFF1 256
#define OFF2 320
#define OFF3 336
#define SLABPX 352   // 256+64+16+16

// ---- ws byte layout ----
#define WIN_OFF 0u                      // int wino[8]: ox[4], oy[4]
#define X0_OFF  4096u                   // int  x0a[4][PP]
#define Y0_OFF  (X0_OFF + 4u*PP*4u)     // int  y0a[4][PP]
#define WX_OFF  (Y0_OFF + 4u*PP*4u)    // float wxa[4][PP]
#define WY_OFF  (WX_OFF + 4u*PP*4u)    // float wya[4][PP]
#define COMP_OFF 262144u                // float comp[128*64][SLABPX]  (11.5 MB)

// ---------------- K1: params + per-level bbox -> window origins ----------------
__global__ __launch_bounds__(256) void k1_params(const float* __restrict__ grid,
    int* __restrict__ wino,
    int* __restrict__ x0a, int* __restrict__ y0a,
    float* __restrict__ wxa, float* __restrict__ wya) {
  __shared__ int smx[4], sMx[4], smy[4], sMy[4];
  int tid = threadIdx.x;
  if (tid < 4) { smx[tid] = 1000; sMx[tid] = -1000; smy[tid] = 1000; sMy[tid] = -1000; }
  __syncthreads();
  int mnx[4] = {1000,1000,1000,1000}, mxx[4] = {-1000,-1000,-1000,-1000};
  int mny[4] = {1000,1000,1000,1000}, mxy[4] = {-1000,-1000,-1000,-1000};
  for (int p = tid; p < NP; p += 256) {
    float gx = fminf(1.f, fmaxf(-1.f, grid[2*p]));
    float gy = fminf(1.f, fmaxf(-1.f, grid[2*p+1]));
    for (int l = 0; l < 4; l++) {
      int W = 64 >> l;
      float ix = (gx + 1.f) * 0.5f * (float)(W - 1);
      float iy = (gy + 1.f) * 0.5f * (float)(W - 1);
      int x0 = (int)floorf(ix); if (x0 > W - 2) x0 = W - 2; if (x0 < 0) x0 = 0;
      int y0 = (int)floorf(iy); if (y0 > W - 2) y0 = W - 2; if (y0 < 0) y0 = 0;
      // ref's clamped-x1 case (ix==W-1): here wx==1, weight shifts to x0+1 -> identical.
      float wx = ix - (float)x0;
      float wy = iy - (float)y0;
      x0a[l*PP+p] = x0; y0a[l*PP+p] = y0; wxa[l*PP+p] = wx; wya[l*PP+p] = wy;
      if (x0 < mnx[l]) mnx[l] = x0;
      if (x0 + 1 > mxx[l]) mxx[l] = x0 + 1;
      if (y0 < mny[l]) mny[l] = y0;
      if (y0 + 1 > mxy[l]) mxy[l] = y0 + 1;
    }
  }
  for (int l = 0; l < 4; l++) {
    atomicMin(&smx[l], mnx[l]); atomicMax(&sMx[l], mxx[l]);
    atomicMin(&smy[l], mny[l]); atomicMax(&sMy[l], mxy[l]);
  }
  __syncthreads();
  if (tid < 4) {
    int l = tid, W = 64 >> l;
    int cap = (l == 0) ? C0 : ((l == 1) ? C1 : C2);
    int ox = smx[l]; if (ox > W - cap) ox = W - cap; if (ox < 0) ox = 0;
    int oy = smy[l]; if (oy > W - cap) oy = W - cap; if (oy < 0) oy = 0;
    wino[l] = ox; wino[4 + l] = oy;
  }
}

// ---------------- K2: gather/pool capped windows into compact slabs ----------------
// grid = 8192 blocks (one per (b,ch) plane), block = 256.
__global__ __launch_bounds__(256) void k2_pool(const float* __restrict__ x,
    const int* __restrict__ wino, float* __restrict__ comp) {
  __shared__ int so[8];
  int t = threadIdx.x;
  if (t < 8) so[t] = wino[t];
  __syncthreads();
  int plane = blockIdx.x;             // b*64 + ch
  int b = plane >> 6, ch = plane & 63;
  int n = b >> 4, tt = b & 15;
  const float* xp = x + ((size_t)(((n*NC + ch) << 4) | tt) << 12);
  float* dst = comp + (size_t)plane * SLABPX;
  { // W0: 16x16 copy
    int ox = so[0], oy = so[4];
    int r = t >> 4, c = t & 15;
    dst[OFF0 + t] = xp[(oy + r) * 64 + ox + c];
  }
  if (t < 64) { // W1: 8x8, each pixel = mean of 2x2
    int ox = so[1], oy = so[5];
    int r = t >> 3, c = t & 7;
    const float* s = xp + ((oy + r) * 2) * 64 + (ox + c) * 2;
    dst[OFF1 + t] = (s[0] + s[1] + s[64] + s[65]) * 0.25f;
  } else if (t < 80) { // W2: 4x4, each = mean of 4x4
    int i = t - 64;
    int ox = so[2], oy = so[6];
    int r = i >> 2, c = i & 3;
    const float* s = xp + ((oy + r) * 4) * 64 + (ox + c) * 4;
    float v = 0.f;
    #pragma unroll
    for (int rr = 0; rr < 4; rr++)
      #pragma unroll
      for (int cc = 0; cc < 4; cc++) v += s[rr*64 + cc];
    dst[OFF2 + i] = v * (1.f/16.f);
  } else if (t < 96) { // W3: 4x4, each = mean of 8x8
    int i = t - 80;
    int ox = so[3], oy = so[7];
    int r = i >> 2, c = i & 3;
    const float* s = xp + ((oy + r) * 8) * 64 + (ox + c) * 8;
    float v = 0.f;
    #pragma unroll
    for (int rr = 0; rr < 8; rr++)
      #pragma unroll
      for (int cc = 0; cc < 8; cc++) v += s[rr*64 + cc];
    dst[OFF3 + i] = v * (1.f/64.f);
  }
}

// ---------------- K3 helpers ----------------
template<int CW>
__device__ __forceinline__ float level_sum(const float* __restrict__ Lp,
                                           const float* __restrict__ fp,
                                           float wx, float wy) {
  float w11 = wx * wy;
  float w01 = wx - w11;
  float w10 = wy - w11;
  float w00 = 1.f - wx - wy + w11;
  float A00 = 0.f, A01 = 0.f, A10 = 0.f, A11 = 0.f;
  #pragma unroll 8
  for (int k = 0; k < NC; k++) {
    float a = Lp[0], bb = Lp[1], c = Lp[CW], d = Lp[CW + 1];
    float f = fp[0];
    A00 += f * a; A01 += f * bb; A10 += f * c; A11 += f * d;
    Lp += SLABPX; fp += NP;
  }
  return w00 * A00 + w01 * A01 + w10 * A10 + w11 * A11;
}

// slow fallback: pool on the fly straight from x (never hit for bench data)
__device__ __noinline__ float level_sum_slow(const float* __restrict__ xpl0, int S,
                                             int x0, int y0,
                                             const float* __restrict__ fp,
                                             float wx, float wy) {
  float w11 = wx * wy, w01 = wx - w11, w10 = wy - w11, w00 = 1.f - wx - wy + w11;
  float A00 = 0.f, A01 = 0.f, A10 = 0.f, A11 = 0.f;
  float inv = 1.f / (float)(S * S);
  for (int k = 0; k < NC; k++) {
    const float* pl = xpl0 + (size_t)k * 65536;
    float v00 = 0.f, v01 = 0.f, v10 = 0.f, v11 = 0.f;
    for (int rr = 0; rr < S; rr++)
      for (int cc = 0; cc < S; cc++) {
        v00 += pl[(y0*S + rr)*64 + x0*S + cc];
        v01 += pl[(y0*S + rr)*64 + (x0+1)*S + cc];
        v10 += pl[((y0+1)*S + rr)*64 + x0*S + cc];
        v11 += pl[((y0+1)*S + rr)*64 + (x0+1)*S + cc];
      }
    float f = fp[0];
    A00 += f * v00 * inv; A01 += f * v01 * inv; A10 += f * v10 * inv; A11 += f * v11 * inv;
    fp += NP;
  }
  return w00 * A00 + w01 * A01 + w10 * A10 + w11 * A11;
}

// ---------------- K3: main contraction ----------------
__global__ __launch_bounds__(256) void k3_main(const float* __restrict__ x,
    const float* __restrict__ feat, const float* __restrict__ bias,
    const float* __restrict__ comp, const int* __restrict__ wino,
    const int* __restrict__ x0a, const int* __restrict__ y0a,
    const float* __restrict__ wxa, const float* __restrict__ wya,
    float* __restrict__ out) {
  int bx = blockIdx.x;                 // 0..1023
  // XCD swizzle: all 8 point-tiles of a given b land on the same XCD (bx%8 heuristic)
  int xcd = bx & 7, j = bx >> 3;
  int b = (xcd << 4) | (j & 15);
  int pt = j >> 4;
  int p = pt * 256 + threadIdx.x;
  int pc = (p < NP) ? p : (NP - 1);
  int n = b >> 4, tt = b & 15;
  const float* base = comp + (size_t)b * NC * SLABPX;
  const float* xpl0 = x + ((size_t)((n << 10) | tt) << 12);  // plane (n, ch=0, tt)
  float acc = 0.f;
  { // level 0
    int x0 = x0a[pc], y0 = y0a[pc];
    float wx = wxa[pc], wy = wya[pc];
    int lx = x0 - wino[0], ly = y0 - wino[4];
    const float* fp = feat + pc;
    if (lx >= 0 && ly >= 0 && lx <= C0 - 2 && ly <= C0 - 2)
      acc += level_sum<C0>(base + OFF0 + ly * C0 + lx, fp, wx, wy);
    else { // direct gather from x
      float w11 = wx*wy, w01 = wx - w11, w10 = wy - w11, w00 = 1.f - wx - wy + w11;
      float A00=0.f, A01=0.f, A10=0.f, A11=0.f;
      const float* Lp = xpl0 + y0 * 64 + x0;
      for (int k = 0; k < NC; k++) {
        float f = fp[0];
        A00 += f*Lp[0]; A01 += f*Lp[1]; A10 += f*Lp[64]; A11 += f*Lp[65];
        Lp += 65536; fp += NP;
      }
      acc += w00*A00 + w01*A01 + w10*A10 + w11*A11;
    }
  }
  { // level 1
    int x0 = x0a[PP+pc], y0 = y0a[PP+pc];
    float wx = wxa[PP+pc], wy = wya[PP+pc];
    int lx = x0 - wino[1], ly = y0 - wino[5];
    const float* fp = feat + NC*NP + pc;
    if (lx >= 0 && ly >= 0 && lx <= C1 - 2 && ly <= C1 - 2)
      acc += level_sum<C1>(base + OFF1 + ly * C1 + lx, fp, wx, wy);
    else
      acc += level_sum_slow(xpl0, 2, x0, y0, fp, wx, wy);
  }
  { // level 2
    int x0 = x0a[2*PP+pc], y0 = y0a[2*PP+pc];
    float wx = wxa[2*PP+pc], wy = wya[2*PP+pc];
    int lx = x0 - wino[2], ly = y0 - wino[6];
    const float* fp = feat + 2*NC*NP + pc;
    if (lx >= 0 && ly >= 0 && lx <= C2 - 2 && ly <= C2 - 2)
      acc += level_sum<C2>(base + OFF2 + ly * C2 + lx, fp, wx, wy);
    else
      acc += level_sum_slow(xpl0, 4, x0, y0, fp, wx, wy);
  }
  { // level 3
    int x0 = x0a[3*PP+pc], y0 = y0a[3*PP+pc];
    float wx = wxa[3*PP+pc], wy = wya[3*PP+pc];
    int lx = x0 - wino[3], ly = y0 - wino[7];
    const float* fp = feat + 3*NC*NP + pc;
    if (lx >= 0 && ly >= 0 && lx <= C3 - 2 && ly <= C3 - 2)
      acc += level_sum<C3>(base + OFF3 + ly * C3 + lx, fp, wx, wy);
    else
      acc += level_sum_slow(xpl0, 8, x0, y0, fp, wx, wy);
  }
  if (p < NP) out[b * NP + p] = acc + bias[p];
}

extern "C" void kernel_launch(void* const* d_in, const int* in_sizes, int n_in,
                              void* d_out, int out_size, void* d_ws, size_t ws_size,
                              hipStream_t stream) {
  (void)in_sizes; (void)n_in; (void)out_size; (void)ws_size;
  const float* x    = (const float*)d_in[0];
  const float* grid = (const float*)d_in[1];
  const float* feat = (const float*)d_in[2];
  const float* bias = (const float*)d_in[3];
  float* out = (float*)d_out;
  char* ws = (char*)d_ws;
  int*   wino = (int*)(ws + WIN_OFF);
  int*   x0a = (int*)(ws + X0_OFF);
  int*   y0a = (int*)(ws + Y0_OFF);
  float* wxa = (float*)(ws + WX_OFF);
  float* wya = (float*)(ws + WY_OFF);
  float* comp = (float*)(ws + COMP_OFF);

  k1_params<<<1, 256, 0, stream>>>(grid, wino, x0a, y0a, wxa, wya);
  k2_pool<<<dim3(NB * NC), 256, 0, stream>>>(x, wino, comp);
  k3_main<<<dim3(1024), 256, 0, stream>>>(x, feat, bias, comp, wino,
                                          x0a, y0a, wxa, wya, out);
}

// Round 3
// 273.278 us; speedup vs baseline: 1.2394x; 1.0900x over previous
//
#include <hip/hip_runtime.h>

#define NP 2000   // points
#define PP 2048   // padded points
#define NB 128    // N*t
#define NC 64     // channels

// window caps (span guaranteed: 0.1*0.5*(W-1)+1 corner <= C-1 for all levels)
#define C0 8
#define C1 6
#define C2 4
#define C3 4
#define Q0 0
#define Q1 64
#define Q2 100
#define Q3 116
#define SLABQ 132          // total window pixels per (b,ch)
#define NBUCK 65           // C0*C0 + 1 overflow

#define K2_EXTRA 514       // featP/biasP copy blocks: 514*256*4 = 257*2048 exactly

// ---- ws layout ----
#define WIN_OFF   0u                         // int wino[8]
#define PERM_OFF  4096u                      // int perm[PP]
#define X0_OFF    (PERM_OFF + PP*4u)         // int  x0a[4][PP]
#define Y0_OFF    (X0_OFF + 4u*PP*4u)
#define WX_OFF    (Y0_OFF + 4u*PP*4u)
#define WY_OFF    (WX_OFF + 4u*PP*4u)
#define BIASP_OFF (WY_OFF + 4u*PP*4u)        // float biasP[PP]
#define FEATP_OFF 262144u                    // float featP[256][PP] = 2 MB
#define COMP4_OFF (FEATP_OFF + 256u*PP*4u)   // float4 comp4[NB][SLABQ][NC] = 17.3 MB

// ---------------- K1: params + bbox + counting sort by level-0 pixel ----------------
__global__ __launch_bounds__(256) void k1_params(const float* __restrict__ grid,
    int* __restrict__ wino, int* __restrict__ perm,
    int* __restrict__ x0a, int* __restrict__ y0a,
    float* __restrict__ wxa, float* __restrict__ wya) {
  __shared__ int smnx[4], smny[4];
  __shared__ int so[8];
  __shared__ int cnt[NBUCK], offs[NBUCK];
  int t = threadIdx.x;
  if (t < 4) { smnx[t] = 1000; smny[t] = 1000; }
  if (t < NBUCK) cnt[t] = 0;
  __syncthreads();
  int mnx[4] = {1000,1000,1000,1000}, mny[4] = {1000,1000,1000,1000};
  for (int p = t; p < NP; p += 256) {
    float gx = fminf(1.f, fmaxf(-1.f, grid[2*p]));
    float gy = fminf(1.f, fmaxf(-1.f, grid[2*p+1]));
    #pragma unroll
    for (int l = 0; l < 4; l++) {
      int W = 64 >> l;
      float ix = (gx + 1.f) * 0.5f * (float)(W - 1);
      float iy = (gy + 1.f) * 0.5f * (float)(W - 1);
      int x0 = min(max((int)floorf(ix), 0), W - 2);
      int y0 = min(max((int)floorf(iy), 0), W - 2);
      mnx[l] = min(mnx[l], x0); mny[l] = min(mny[l], y0);
    }
  }
  #pragma unroll
  for (int l = 0; l < 4; l++) { atomicMin(&smnx[l], mnx[l]); atomicMin(&smny[l], mny[l]); }
  __syncthreads();
  if (t < 4) {
    int l = t, W = 64 >> l;
    int cap = (l == 0) ? C0 : (l == 1) ? C1 : (l == 2) ? C2 : C3;
    int ox = min(max(smnx[l], 0), W - cap);
    int oy = min(max(smny[l], 0), W - cap);
    so[l] = ox; so[4+l] = oy; wino[l] = ox; wino[4+l] = oy;
  }
  __syncthreads();
  // histogram over level-0 buckets
  for (int p = t; p < NP; p += 256) {
    float gx = fminf(1.f, fmaxf(-1.f, grid[2*p]));
    float gy = fminf(1.f, fmaxf(-1.f, grid[2*p+1]));
    float ix = (gx + 1.f) * 0.5f * 63.f, iy = (gy + 1.f) * 0.5f * 63.f;
    int x0 = min(max((int)floorf(ix), 0), 62), y0 = min(max((int)floorf(iy), 0), 62);
    int lx = x0 - so[0], ly = y0 - so[4];
    int bkt = (lx >= 0 && ly >= 0 && lx <= C0-2 && ly <= C0-2) ? ly*C0 + lx : NBUCK-1;
    atomicAdd(&cnt[bkt], 1);
  }
  __syncthreads();
  if (t == 0) { int s = 0; for (int i = 0; i < NBUCK; i++) { offs[i] = s; s += cnt[i]; } }
  __syncthreads();
  // placement + permuted param writes
  for (int p = t; p < NP; p += 256) {
    float gx = fminf(1.f, fmaxf(-1.f, grid[2*p]));
    float gy = fminf(1.f, fmaxf(-1.f, grid[2*p+1]));
    float ix = (gx + 1.f) * 0.5f * 63.f, iy = (gy + 1.f) * 0.5f * 63.f;
    int x0 = min(max((int)floorf(ix), 0), 62), y0 = min(max((int)floorf(iy), 0), 62);
    int lx = x0 - so[0], ly = y0 - so[4];
    int bkt = (lx >= 0 && ly >= 0 && lx <= C0-2 && ly <= C0-2) ? ly*C0 + lx : NBUCK-1;
    int slot = atomicAdd(&offs[bkt], 1);
    perm[slot] = p;
    #pragma unroll
    for (int l = 0; l < 4; l++) {
      int W = 64 >> l;
      float ix2 = (gx + 1.f) * 0.5f * (float)(W - 1);
      float iy2 = (gy + 1.f) * 0.5f * (float)(W - 1);
      int xx = min(max((int)floorf(ix2), 0), W - 2);
      int yy = min(max((int)floorf(iy2), 0), W - 2);
      // ref's clamped case (ix==W-1): wx becomes 1, weight shifts to xx+1 -> identical
      x0a[l*PP+slot] = xx; y0a[l*PP+slot] = yy;
      wxa[l*PP+slot] = ix2 - (float)xx; wya[l*PP+slot] = iy2 - (float)yy;
    }
  }
}

// ---------------- K2: pooled windows -> corner-packed comp4; featP/biasP copies --------
__global__ __launch_bounds__(256) void k2_pool(const float* __restrict__ x,
    const int* __restrict__ wino, const int* __restrict__ perm,
    const float* __restrict__ feat, const float* __restrict__ bias,
    float4* __restrict__ comp4, float* __restrict__ featP, float* __restrict__ biasP) {
  int t = threadIdx.x;
  int bx = blockIdx.x;
  if (bx >= NB*NC) {
    int idx = (bx - NB*NC) * 256 + t;           // [0, 131584)
    #pragma unroll
    for (int j = 0; j < 4; j++) {
      int e = idx + j * (K2_EXTRA * 256);       // [0, 526336) exactly
      int r = e >> 11, i = e & 2047;
      int pm = (i < NP) ? perm[i] : 0;
      if (r < 256) featP[(r << 11) + i] = (i < NP) ? feat[r*NP + pm] : 0.f;
      else         biasP[i]            = (i < NP) ? bias[pm] : 0.f;
    }
    return;
  }
  __shared__ float win[SLABQ];
  __shared__ float part3[64];
  __shared__ int so[8];
  if (t < 8) so[t] = wino[t];
  __syncthreads();
  int b = bx >> 6, ch = bx & 63;
  int n = b >> 4, tt = b & 15;
  const float* xp = x + ((size_t)(((n*NC + ch) << 4) | tt) << 12);
  if (t < 64) {               // l0: 8x8 copy
    int r = t >> 3, c = t & 7;
    win[Q0 + t] = xp[(so[4]+r)*64 + so[0]+c];
  } else if (t < 100) {       // l1: 6x6, mean of 2x2
    int i = t - 64; int r = i / 6, c = i - r*6;
    const float* s = xp + ((so[5]+r)*2)*64 + (so[1]+c)*2;
    win[Q1 + i] = (s[0] + s[1] + s[64] + s[65]) * 0.25f;
  } else if (t < 116) {       // l2: 4x4, mean of 4x4
    int i = t - 100; int r = i >> 2, c = i & 3;
    const float* s = xp + ((so[6]+r)*4)*64 + (so[2]+c)*4;
    float v = 0.f;
    #pragma unroll
    for (int rr = 0; rr < 4; rr++)
      #pragma unroll
      for (int cc = 0; cc < 4; cc++) v += s[rr*64 + cc];
    win[Q2 + i] = v * (1.f/16.f);
  } else if (t < 180) {       // l3: 4x4, mean of 8x8 -- 4 partials per px (2 rows each)
    int i = t - 116; int px = i >> 2, part = i & 3;
    int r = px >> 2, c = px & 3;
    const float* s = xp + ((so[7]+r)*8 + part*2)*64 + (so[3]+c)*8;
    float v = 0.f;
    #pragma unroll
    for (int rr = 0; rr < 2; rr++)
      #pragma unroll
      for (int cc = 0; cc < 8; cc++) v += s[rr*64 + cc];
    part3[i] = v;
  }
  __syncthreads();
  if (t < 16) win[Q3 + t] = (part3[4*t] + part3[4*t+1] + part3[4*t+2] + part3[4*t+3]) * (1.f/64.f);
  __syncthreads();
  if (t < SLABQ) {
    int q = t, base, C, loc, ly, lx;
    if (q < Q1)      { base = Q0; C = C0; loc = q - base; ly = loc >> 3; lx = loc & 7; }
    else if (q < Q2) { base = Q1; C = C1; loc = q - base; ly = loc / 6; lx = loc - ly*6; }
    else if (q < Q3) { base = Q2; C = C2; loc = q - base; ly = loc >> 2; lx = loc & 3; }
    else             { base = Q3; C = C3; loc = q - base; ly = loc >> 2; lx = loc & 3; }
    int lx1 = min(lx + 1, C - 1), ly1 = min(ly + 1, C - 1);
    float4 v;
    v.x = win[base + ly*C  + lx];
    v.y = win[base + ly*C  + lx1];
    v.z = win[base + ly1*C + lx];
    v.w = win[base + ly1*C + lx1];
    comp4[(((size_t)(b*SLABQ + q)) << 6) + ch] = v;
  }
}

// ---------------- K3 helpers ----------------
__device__ __forceinline__ float level_sum(const float4* __restrict__ Lp4,
                                           const float* __restrict__ fp,
                                           float wx, float wy) {
  float w11 = wx*wy, w01 = wx - w11, w10 = wy - w11, w00 = 1.f - wx - wy + w11;
  float A00 = 0.f, A01 = 0.f, A10 = 0.f, A11 = 0.f;
  #pragma unroll 8
  for (int k = 0; k < NC; k++) {
    float4 v = Lp4[k];
    float f = fp[k << 11];          // featP stride PP=2048
    A00 += f*v.x; A01 += f*v.y; A10 += f*v.z; A11 += f*v.w;
  }
  return w00*A00 + w01*A01 + w10*A10 + w11*A11;
}

// slow fallback: pool on the fly straight from x (never hit for bench data)
__device__ __noinline__ float level_sum_slow(const float* __restrict__ xpl0, int S,
                                             int x0, int y0,
                                             const float* __restrict__ fp,
                                             float wx, float wy) {
  float w11 = wx*wy, w01 = wx - w11, w10 = wy - w11, w00 = 1.f - wx - wy + w11;
  float A00 = 0.f, A01 = 0.f, A10 = 0.f, A11 = 0.f;
  float inv = 1.f / (float)(S * S);
  for (int k = 0; k < NC; k++) {
    const float* pl = xpl0 + (size_t)k * 65536;
    float v00 = 0.f, v01 = 0.f, v10 = 0.f, v11 = 0.f;
    for (int rr = 0; rr < S; rr++)
      for (int cc = 0; cc < S; cc++) {
        v00 += pl[(y0*S + rr)*64 + x0*S + cc];
        v01 += pl[(y0*S + rr)*64 + (x0+1)*S + cc];
        v10 += pl[((y0+1)*S + rr)*64 + x0*S + cc];
        v11 += pl[((y0+1)*S + rr)*64 + (x0+1)*S + cc];
      }
    float f = fp[0];
    A00 += f*v00*inv; A01 += f*v01*inv; A10 += f*v10*inv; A11 += f*v11*inv;
    fp += PP;
  }
  return w00*A00 + w01*A01 + w10*A10 + w11*A11;
}

// ---------------- K3: main contraction (sorted index space) ----------------
__global__ __launch_bounds__(256) void k3_main(const float* __restrict__ x,
    const float* __restrict__ featP, const float* __restrict__ biasP,
    const float4* __restrict__ comp4, const int* __restrict__ wino,
    const int* __restrict__ perm,
    const int* __restrict__ x0a, const int* __restrict__ y0a,
    const float* __restrict__ wxa, const float* __restrict__ wya,
    float* __restrict__ out) {
  int bx = blockIdx.x;                 // 0..1023
  int xcd = bx & 7, j = bx >> 3;       // all 8 p-tiles of a b on one XCD
  int b = (xcd << 4) | (j & 15);
  int pt = j >> 4;
  int i = pt * 256 + threadIdx.x;
  if (i >= NP) return;
  int n = b >> 4, tt = b & 15;
  const float* xpl0 = x + ((size_t)((n << 10) | tt) << 12);
  const float4* cb = comp4 + ((size_t)(b * SLABQ) << 6);
  float acc = 0.f;
  { // level 0
    int x0 = x0a[i], y0 = y0a[i];
    float wx = wxa[i], wy = wya[i];
    int lx = x0 - wino[0], ly = y0 - wino[4];
    const float* fp = featP + i;
    if (lx >= 0 && ly >= 0 && lx <= C0-2 && ly <= C0-2)
      acc += level_sum(cb + ((size_t)(Q0 + ly*C0 + lx) << 6), fp, wx, wy);
    else {
      float w11 = wx*wy, w01 = wx - w11, w10 = wy - w11, w00 = 1.f - wx - wy + w11;
      float A00 = 0.f, A01 = 0.f, A10 = 0.f, A11 = 0.f;
      const float* Lp = xpl0 + y0*64 + x0;
      for (int k = 0; k < NC; k++) {
        float f = fp[0];
        A00 += f*Lp[0]; A01 += f*Lp[1]; A10 += f*Lp[64]; A11 += f*Lp[65];
        Lp += 65536; fp += PP;
      }
      acc += w00*A00 + w01*A01 + w10*A10 + w11*A11;
    }
  }
  { // level 1
    int x0 = x0a[PP+i], y0 = y0a[PP+i];
    float wx = wxa[PP+i], wy = wya[PP+i];
    int lx = x0 - wino[1], ly = y0 - wino[5];
    const float* fp = featP + (1 << 17) + i;
    if (lx >= 0 && ly >= 0 && lx <= C1-2 && ly <= C1-2)
      acc += level_sum(cb + ((size_t)(Q1 + ly*C1 + lx) << 6), fp, wx, wy);
    else
      acc += level_sum_slow(xpl0, 2, x0, y0, fp, wx, wy);
  }
  { // level 2
    int x0 = x0a[2*PP+i], y0 = y0a[2*PP+i];
    float wx = wxa[2*PP+i], wy = wya[2*PP+i];
    int lx = x0 - wino[2], ly = y0 - wino[6];
    const float* fp = featP + (2 << 17) + i;
    if (lx >= 0 && ly >= 0 && lx <= C2-2 && ly <= C2-2)
      acc += level_sum(cb + ((size_t)(Q2 + ly*C2 + lx) << 6), fp, wx, wy);
    else
      acc += level_sum_slow(xpl0, 4, x0, y0, fp, wx, wy);
  }
  { // level 3
    int x0 = x0a[3*PP+i], y0 = y0a[3*PP+i];
    float wx = wxa[3*PP+i], wy = wya[3*PP+i];
    int lx = x0 - wino[3], ly = y0 - wino[7];
    const float* fp = featP + (3 << 17) + i;
    if (lx >= 0 && ly >= 0 && lx <= C3-2 && ly <= C3-2)
      acc += level_sum(cb + ((size_t)(Q3 + ly*C3 + lx) << 6), fp, wx, wy);
    else
      acc += level_sum_slow(xpl0, 8, x0, y0, fp, wx, wy);
  }
  out[b*NP + perm[i]] = acc + biasP[i];
}

extern "C" void kernel_launch(void* const* d_in, const int* in_sizes, int n_in,
                              void* d_out, int out_size, void* d_ws, size_t ws_size,
                              hipStream_t stream) {
  (void)in_sizes; (void)n_in; (void)out_size; (void)ws_size;
  const float* x    = (const float*)d_in[0];
  const float* grid = (const float*)d_in[1];
  const float* feat = (const float*)d_in[2];
  const float* bias = (const float*)d_in[3];
  float* out = (float*)d_out;
  char* ws = (char*)d_ws;
  int*    wino  = (int*)(ws + WIN_OFF);
  int*    perm  = (int*)(ws + PERM_OFF);
  int*    x0a   = (int*)(ws + X0_OFF);
  int*    y0a   = (int*)(ws + Y0_OFF);
  float*  wxa   = (float*)(ws + WX_OFF);
  float*  wya   = (float*)(ws + WY_OFF);
  float*  biasP = (float*)(ws + BIASP_OFF);
  float*  featP = (float*)(ws + FEATP_OFF);
  float4* comp4 = (float4*)(ws + COMP4_OFF);

  k1_params<<<1, 256, 0, stream>>>(grid, wino, perm, x0a, y0a, wxa, wya);
  k2_pool<<<dim3(NB*NC + K2_EXTRA), 256, 0, stream>>>(x, wino, perm, feat, bias,
                                                      comp4, featP, biasP);
  k3_main<<<dim3(1024), 256, 0, stream>>>(x, featP, biasP, comp4, wino, perm,
                                          x0a, y0a, wxa, wya, out);
}

// Round 4
// 259.676 us; speedup vs baseline: 1.3043x; 1.0524x over previous
//
#include <hip/hip_runtime.h>

#define NP 2000   // points
#define PP 2048   // padded points
#define NB 128    // N*t
#define NC 64     // channels

// window caps (span guaranteed for |grid|<=0.05; fallback path covers the rest)
#define C0 8
#define C1 6
#define C2 4
#define C3 4
#define Q0 0
#define Q1 64
#define Q2 100
#define Q3 116
#define SLABQ 132          // total window pixels per (b,ch)
#define NBUCK 65           // C0*C0 + 1 overflow

#define K2_EXTRA 514       // featP/biasP copy blocks: 514*256*4 = 257*2048 exactly

typedef float f32x2 __attribute__((ext_vector_type(2)));

// ---- ws layout ----
#define WIN_OFF   0u                         // int wino[8]
#define PERM_OFF  4096u                      // int perm[PP]
#define X0_OFF    (PERM_OFF + PP*4u)         // int  x0a[4][PP]
#define Y0_OFF    (X0_OFF + 4u*PP*4u)
#define WX_OFF    (Y0_OFF + 4u*PP*4u)
#define WY_OFF    (WX_OFF + 4u*PP*4u)
#define BIASP_OFF (WY_OFF + 4u*PP*4u)        // float biasP[PP]
#define FEATP_OFF 262144u                    // float featP[256][PP] = 2 MB
#define COMP4_OFF (FEATP_OFF + 256u*PP*4u)   // float4 comp4[NB][NC][SLABQ] = 17.3 MB

// ---------------- K1: params + bbox + counting sort by level-0 pixel ----------------
__global__ __launch_bounds__(256) void k1_params(const float* __restrict__ grid,
    int* __restrict__ wino, int* __restrict__ perm,
    int* __restrict__ x0a, int* __restrict__ y0a,
    float* __restrict__ wxa, float* __restrict__ wya) {
  __shared__ int smnx[4], smny[4];
  __shared__ int so[8];
  __shared__ int cnt[NBUCK], offs[NBUCK];
  int t = threadIdx.x;
  if (t < 4) { smnx[t] = 1000; smny[t] = 1000; }
  if (t < NBUCK) cnt[t] = 0;
  __syncthreads();
  int mnx[4] = {1000,1000,1000,1000}, mny[4] = {1000,1000,1000,1000};
  for (int p = t; p < NP; p += 256) {
    float gx = fminf(1.f, fmaxf(-1.f, grid[2*p]));
    float gy = fminf(1.f, fmaxf(-1.f, grid[2*p+1]));
    #pragma unroll
    for (int l = 0; l < 4; l++) {
      int W = 64 >> l;
      float ix = (gx + 1.f) * 0.5f * (float)(W - 1);
      float iy = (gy + 1.f) * 0.5f * (float)(W - 1);
      int x0 = min(max((int)floorf(ix), 0), W - 2);
      int y0 = min(max((int)floorf(iy), 0), W - 2);
      mnx[l] = min(mnx[l], x0); mny[l] = min(mny[l], y0);
    }
  }
  #pragma unroll
  for (int l = 0; l < 4; l++) { atomicMin(&smnx[l], mnx[l]); atomicMin(&smny[l], mny[l]); }
  __syncthreads();
  if (t < 4) {
    int l = t, W = 64 >> l;
    int cap = (l == 0) ? C0 : (l == 1) ? C1 : (l == 2) ? C2 : C3;
    int ox = min(max(smnx[l], 0), W - cap);
    int oy = min(max(smny[l], 0), W - cap);
    so[l] = ox; so[4+l] = oy; wino[l] = ox; wino[4+l] = oy;
  }
  __syncthreads();
  // histogram over level-0 buckets
  for (int p = t; p < NP; p += 256) {
    float gx = fminf(1.f, fmaxf(-1.f, grid[2*p]));
    float gy = fminf(1.f, fmaxf(-1.f, grid[2*p+1]));
    float ix = (gx + 1.f) * 0.5f * 63.f, iy = (gy + 1.f) * 0.5f * 63.f;
    int x0 = min(max((int)floorf(ix), 0), 62), y0 = min(max((int)floorf(iy), 0), 62);
    int lx = x0 - so[0], ly = y0 - so[4];
    int bkt = (lx >= 0 && ly >= 0 && lx <= C0-2 && ly <= C0-2) ? ly*C0 + lx : NBUCK-1;
    atomicAdd(&cnt[bkt], 1);
  }
  __syncthreads();
  if (t == 0) { int s = 0; for (int i = 0; i < NBUCK; i++) { offs[i] = s; s += cnt[i]; } }
  __syncthreads();
  // placement + permuted param writes
  for (int p = t; p < NP; p += 256) {
    float gx = fminf(1.f, fmaxf(-1.f, grid[2*p]));
    float gy = fminf(1.f, fmaxf(-1.f, grid[2*p+1]));
    float ix = (gx + 1.f) * 0.5f * 63.f, iy = (gy + 1.f) * 0.5f * 63.f;
    int x0 = min(max((int)floorf(ix), 0), 62), y0 = min(max((int)floorf(iy), 0), 62);
    int lx = x0 - so[0], ly = y0 - so[4];
    int bkt = (lx >= 0 && ly >= 0 && lx <= C0-2 && ly <= C0-2) ? ly*C0 + lx : NBUCK-1;
    int slot = atomicAdd(&offs[bkt], 1);
    perm[slot] = p;
    #pragma unroll
    for (int l = 0; l < 4; l++) {
      int W = 64 >> l;
      float ix2 = (gx + 1.f) * 0.5f * (float)(W - 1);
      float iy2 = (gy + 1.f) * 0.5f * (float)(W - 1);
      int xx = min(max((int)floorf(ix2), 0), W - 2);
      int yy = min(max((int)floorf(iy2), 0), W - 2);
      // ref's clamped case (ix==W-1): wx becomes 1, weight shifts to xx+1 -> identical
      x0a[l*PP+slot] = xx; y0a[l*PP+slot] = yy;
      wxa[l*PP+slot] = ix2 - (float)xx; wya[l*PP+slot] = iy2 - (float)yy;
    }
  }
}

// ---------------- K2: pooled windows -> corner-packed comp4 [b][ch][q]; featP/biasP ----
__global__ __launch_bounds__(256) void k2_pool(const float* __restrict__ x,
    const int* __restrict__ wino, const int* __restrict__ perm,
    const float* __restrict__ feat, const float* __restrict__ bias,
    float4* __restrict__ comp4, float* __restrict__ featP, float* __restrict__ biasP) {
  int t = threadIdx.x;
  int bx = blockIdx.x;
  if (bx >= NB*NC) {
    int idx = (bx - NB*NC) * 256 + t;           // [0, 131584)
    #pragma unroll
    for (int j = 0; j < 4; j++) {
      int e = idx + j * (K2_EXTRA * 256);       // [0, 526336) exactly
      int r = e >> 11, i = e & 2047;
      int pm = (i < NP) ? perm[i] : 0;
      if (r < 256) featP[(r << 11) + i] = (i < NP) ? feat[r*NP + pm] : 0.f;
      else         biasP[i]            = (i < NP) ? bias[pm] : 0.f;
    }
    return;
  }
  __shared__ float win[SLABQ];
  __shared__ float part3[64];
  __shared__ int so[8];
  if (t < 8) so[t] = wino[t];
  __syncthreads();
  int b = bx >> 6, ch = bx & 63;
  int n = b >> 4, tt = b & 15;
  const float* xp = x + ((size_t)(((n*NC + ch) << 4) | tt) << 12);
  if (t < 64) {               // l0: 8x8 copy
    int r = t >> 3, c = t & 7;
    win[Q0 + t] = xp[(so[4]+r)*64 + so[0]+c];
  } else if (t < 100) {       // l1: 6x6, mean of 2x2
    int i = t - 64; int r = i / 6, c = i - r*6;
    const float* s = xp + ((so[5]+r)*2)*64 + (so[1]+c)*2;
    win[Q1 + i] = (s[0] + s[1] + s[64] + s[65]) * 0.25f;
  } else if (t < 116) {       // l2: 4x4, mean of 4x4
    int i = t - 100; int r = i >> 2, c = i & 3;
    const float* s = xp + ((so[6]+r)*4)*64 + (so[2]+c)*4;
    float v = 0.f;
    #pragma unroll
    for (int rr = 0; rr < 4; rr++)
      #pragma unroll
      for (int cc = 0; cc < 4; cc++) v += s[rr*64 + cc];
    win[Q2 + i] = v * (1.f/16.f);
  } else if (t < 180) {       // l3: 4x4, mean of 8x8 -- 4 partials per px (2 rows each)
    int i = t - 116; int px = i >> 2, part = i & 3;
    int r = px >> 2, c = px & 3;
    const float* s = xp + ((so[7]+r)*8 + part*2)*64 + (so[3]+c)*8;
    float v = 0.f;
    #pragma unroll
    for (int rr = 0; rr < 2; rr++)
      #pragma unroll
      for (int cc = 0; cc < 8; cc++) v += s[rr*64 + cc];
    part3[i] = v;
  }
  __syncthreads();
  if (t < 16) win[Q3 + t] = (part3[4*t] + part3[4*t+1] + part3[4*t+2] + part3[4*t+3]) * (1.f/64.f);
  __syncthreads();
  if (t < SLABQ) {
    int q = t, base, C, loc, ly, lx;
    if (q < Q1)      { base = Q0; C = C0; loc = q - base; ly = loc >> 3; lx = loc & 7; }
    else if (q < Q2) { base = Q1; C = C1; loc = q - base; ly = loc / 6; lx = loc - ly*6; }
    else if (q < Q3) { base = Q2; C = C2; loc = q - base; ly = loc >> 2; lx = loc & 3; }
    else             { base = Q3; C = C3; loc = q - base; ly = loc >> 2; lx = loc & 3; }
    int lx1 = min(lx + 1, C - 1), ly1 = min(ly + 1, C - 1);
    float4 v;
    v.x = win[base + ly*C  + lx];
    v.y = win[base + ly*C  + lx1];
    v.z = win[base + ly1*C + lx];
    v.w = win[base + ly1*C + lx1];
    // [b][ch][q] layout: block writes a contiguous 2112B burst (coalesced)
    comp4[(size_t)(b*NC + ch)*SLABQ + q] = v;
  }
}

// ---------------- K3 helpers ----------------
// cbq = comp4 + b*NC*SLABQ + q; k-stride = SLABQ float4s. Packed f32x2 accumulation.
__device__ __forceinline__ float level_sum(const float4* __restrict__ cbq,
                                           const float* __restrict__ fp,
                                           float wx, float wy) {
  float w11 = wx*wy, w01 = wx - w11, w10 = wy - w11, w00 = 1.f - wx - wy + w11;
  f32x2 A0 = {0.f, 0.f}, A1 = {0.f, 0.f};
  #pragma unroll 8
  for (int k = 0; k < NC; k++) {
    float4 v = cbq[(size_t)k * SLABQ];
    float f = fp[k << 11];          // featP stride PP=2048
    f32x2 vf = {f, f};
    f32x2 v01 = {v.x, v.y}, v23 = {v.z, v.w};
    A0 += vf * v01;                 // v_pk_fma_f32 candidates
    A1 += vf * v23;
  }
  return w00*A0.x + w01*A0.y + w10*A1.x + w11*A1.y;
}

// slow fallback: pool on the fly straight from x (never hit for bench data)
__device__ __noinline__ float level_sum_slow(const float* __restrict__ xpl0, int S,
                                             int x0, int y0,
                                             const float* __restrict__ fp,
                                             float wx, float wy) {
  float w11 = wx*wy, w01 = wx - w11, w10 = wy - w11, w00 = 1.f - wx - wy + w11;
  float A00 = 0.f, A01 = 0.f, A10 = 0.f, A11 = 0.f;
  float inv = 1.f / (float)(S * S);
  for (int k = 0; k < NC; k++) {
    const float* pl = xpl0 + (size_t)k * 65536;
    float v00 = 0.f, v01 = 0.f, v10 = 0.f, v11 = 0.f;
    for (int rr = 0; rr < S; rr++)
      for (int cc = 0; cc < S; cc++) {
        v00 += pl[(y0*S + rr)*64 + x0*S + cc];
        v01 += pl[(y0*S + rr)*64 + (x0+1)*S + cc];
        v10 += pl[((y0+1)*S + rr)*64 + x0*S + cc];
        v11 += pl[((y0+1)*S + rr)*64 + (x0+1)*S + cc];
      }
    float f = fp[0];
    A00 += f*v00*inv; A01 += f*v01*inv; A10 += f*v10*inv; A11 += f*v11*inv;
    fp += PP;
  }
  return w00*A00 + w01*A01 + w10*A10 + w11*A11;
}

// ---------------- K3: main contraction (sorted index space) ----------------
__global__ __launch_bounds__(256) void k3_main(const float* __restrict__ x,
    const float* __restrict__ featP, const float* __restrict__ biasP,
    const float4* __restrict__ comp4, const int* __restrict__ wino,
    const int* __restrict__ perm,
    const int* __restrict__ x0a, const int* __restrict__ y0a,
    const float* __restrict__ wxa, const float* __restrict__ wya,
    float* __restrict__ out) {
  int bx = blockIdx.x;                 // 0..1023
  int xcd = bx & 7, j = bx >> 3;       // all 8 p-tiles of a b on one XCD
  int b = (xcd << 4) | (j & 15);
  int pt = j >> 4;
  int i = pt * 256 + threadIdx.x;
  if (i >= NP) return;
  int n = b >> 4, tt = b & 15;
  const float* xpl0 = x + ((size_t)((n << 10) | tt) << 12);
  const float4* cb = comp4 + (size_t)b * NC * SLABQ;
  float acc = 0.f;
  { // level 0
    int x0 = x0a[i], y0 = y0a[i];
    float wx = wxa[i], wy = wya[i];
    int lx = x0 - wino[0], ly = y0 - wino[4];
    const float* fp = featP + i;
    if (lx >= 0 && ly >= 0 && lx <= C0-2 && ly <= C0-2)
      acc += level_sum(cb + (Q0 + ly*C0 + lx), fp, wx, wy);
    else {
      float w11 = wx*wy, w01 = wx - w11, w10 = wy - w11, w00 = 1.f - wx - wy + w11;
      float A00 = 0.f, A01 = 0.f, A10 = 0.f, A11 = 0.f;
      const float* Lp = xpl0 + y0*64 + x0;
      for (int k = 0; k < NC; k++) {
        float f = fp[0];
        A00 += f*Lp[0]; A01 += f*Lp[1]; A10 += f*Lp[64]; A11 += f*Lp[65];
        Lp += 65536; fp += PP;
      }
      acc += w00*A00 + w01*A01 + w10*A10 + w11*A11;
    }
  }
  { // level 1
    int x0 = x0a[PP+i], y0 = y0a[PP+i];
    float wx = wxa[PP+i], wy = wya[PP+i];
    int lx = x0 - wino[1], ly = y0 - wino[5];
    const float* fp = featP + (1 << 17) + i;
    if (lx >= 0 && ly >= 0 && lx <= C1-2 && ly <= C1-2)
      acc += level_sum(cb + (Q1 + ly*C1 + lx), fp, wx, wy);
    else
      acc += level_sum_slow(xpl0, 2, x0, y0, fp, wx, wy);
  }
  { // level 2
    int x0 = x0a[2*PP+i], y0 = y0a[2*PP+i];
    float wx = wxa[2*PP+i], wy = wya[2*PP+i];
    int lx = x0 - wino[2], ly = y0 - wino[6];
    const float* fp = featP + (2 << 17) + i;
    if (lx >= 0 && ly >= 0 && lx <= C2-2 && ly <= C2-2)
      acc += level_sum(cb + (Q2 + ly*C2 + lx), fp, wx, wy);
    else
      acc += level_sum_slow(xpl0, 4, x0, y0, fp, wx, wy);
  }
  { // level 3
    int x0 = x0a[3*PP+i], y0 = y0a[3*PP+i];
    float wx = wxa[3*PP+i], wy = wya[3*PP+i];
    int lx = x0 - wino[3], ly = y0 - wino[7];
    const float* fp = featP + (3 << 17) + i;
    if (lx >= 0 && ly >= 0 && lx <= C3-2 && ly <= C3-2)
      acc += level_sum(cb + (Q3 + ly*C3 + lx), fp, wx, wy);
    else
      acc += level_sum_slow(xpl0, 8, x0, y0, fp, wx, wy);
  }
  out[b*NP + perm[i]] = acc + biasP[i];
}

extern "C" void kernel_launch(void* const* d_in, const int* in_sizes, int n_in,
                              void* d_out, int out_size, void* d_ws, size_t ws_size,
                              hipStream_t stream) {
  (void)in_sizes; (void)n_in; (void)out_size; (void)ws_size;
  const float* x    = (const float*)d_in[0];
  const float* grid = (const float*)d_in[1];
  const float* feat = (const float*)d_in[2];
  const float* bias = (const float*)d_in[3];
  float* out = (float*)d_out;
  char* ws = (char*)d_ws;
  int*    wino  = (int*)(ws + WIN_OFF);
  int*    perm  = (int*)(ws + PERM_OFF);
  int*    x0a   = (int*)(ws + X0_OFF);
  int*    y0a   = (int*)(ws + Y0_OFF);
  float*  wxa   = (float*)(ws + WX_OFF);
  float*  wya   = (float*)(ws + WY_OFF);
  float*  biasP = (float*)(ws + BIASP_OFF);
  float*  featP = (float*)(ws + FEATP_OFF);
  float4* comp4 = (float4*)(ws + COMP4_OFF);

  k1_params<<<1, 256, 0, stream>>>(grid, wino, perm, x0a, y0a, wxa, wya);
  k2_pool<<<dim3(NB*NC + K2_EXTRA), 256, 0, stream>>>(x, wino, perm, feat, bias,
                                                      comp4, featP, biasP);
  k3_main<<<dim3(1024), 256, 0, stream>>>(x, featP, biasP, comp4, wino, perm,
                                          x0a, y0a, wxa, wya, out);
}